// Round 1
// baseline (96.648 us; speedup 1.0000x reference)
//
#include <hip/hip_runtime.h>
#include <hip/hip_bf16.h>
#include <math.h>

#define N_SUBWORDS 8192
#define N_WORDS    6000
#define HIDDEN     1024

// Kernel 1: per-subword scalar score = dot(hidden[s], w) + b
// One wave (64 lanes) per subword row. 1024 floats = 256 float4; 64 lanes x 4 iters.
__global__ __launch_bounds__(256) void coref_scores_kernel(
    const float* __restrict__ hs,     // [N_SUBWORDS, HIDDEN]
    const float* __restrict__ w_attn, // [HIDDEN]
    const float* __restrict__ b_attn, // [1]
    float* __restrict__ scores)       // [N_SUBWORDS]
{
    const int gtid = blockIdx.x * blockDim.x + threadIdx.x;
    const int row  = gtid >> 6;          // wave index == subword row
    const int lane = threadIdx.x & 63;
    if (row >= N_SUBWORDS) return;

    const float4* __restrict__ hrow = (const float4*)(hs + (size_t)row * HIDDEN);
    const float4* __restrict__ wv   = (const float4*)w_attn;

    float sum = 0.f;
#pragma unroll
    for (int i = 0; i < 4; ++i) {
        const int idx = lane + 64 * i;
        float4 h  = hrow[idx];
        float4 ww = wv[idx];
        sum += h.x * ww.x + h.y * ww.y + h.z * ww.z + h.w * ww.w;
    }
    // wave-64 butterfly reduce
#pragma unroll
    for (int off = 32; off > 0; off >>= 1)
        sum += __shfl_down(sum, off, 64);

    if (lane == 0)
        scores[row] = sum + b_attn[0];
}

// Kernel 2: one block per word. Softmax over the (tiny, contiguous) span of
// scores, then weighted sum of the span's hidden rows into out[word].
// 256 threads x float4 = 1024 hidden dims.
__global__ __launch_bounds__(256) void coref_pool_kernel(
    const float* __restrict__ hs,      // [N_SUBWORDS, HIDDEN]
    const int*   __restrict__ starts,  // [N_WORDS]
    const int*   __restrict__ ends,    // [N_WORDS] inclusive
    const float* __restrict__ scores,  // [N_SUBWORDS]
    float*       __restrict__ out)     // [N_WORDS, HIDDEN]
{
    const int w = blockIdx.x;
    if (w >= N_WORDS) return;

    const int s0 = starts[w];
    const int s1 = ends[w];   // inclusive, >= s0

    // All threads compute softmax stats redundantly: span is ~1-2 elements on
    // average and scores[s] is a wave-uniform broadcast load (L2-hot).
    float m = -INFINITY;
    for (int s = s0; s <= s1; ++s)
        m = fmaxf(m, scores[s]);
    float l = 0.f;
    for (int s = s0; s <= s1; ++s)
        l += expf(scores[s] - m);
    const float inv_l = 1.f / l;

    const int d = threadIdx.x * 4;
    float4 acc = make_float4(0.f, 0.f, 0.f, 0.f);
    for (int s = s0; s <= s1; ++s) {
        const float wt = expf(scores[s] - m) * inv_l;
        float4 h = *(const float4*)(hs + (size_t)s * HIDDEN + d);
        acc.x += wt * h.x;
        acc.y += wt * h.y;
        acc.z += wt * h.z;
        acc.w += wt * h.w;
    }
    *(float4*)(out + (size_t)w * HIDDEN + d) = acc;
}

extern "C" void kernel_launch(void* const* d_in, const int* in_sizes, int n_in,
                              void* d_out, int out_size, void* d_ws, size_t ws_size,
                              hipStream_t stream) {
    const float* hs      = (const float*)d_in[0];  // [8192*1024] f32
    const int*   starts  = (const int*)d_in[1];    // [6000] int
    const int*   ends    = (const int*)d_in[2];    // [6000] int
    const float* w_attn  = (const float*)d_in[3];  // [1024] f32
    const float* b_attn  = (const float*)d_in[4];  // [1] f32
    float*       out     = (float*)d_out;          // [6000*1024] f32
    float*       scores  = (float*)d_ws;           // [8192] f32 scratch

    // K1: 8192 rows, one wave each -> 8192*64 threads / 256 = 2048 blocks
    coref_scores_kernel<<<dim3((N_SUBWORDS * 64) / 256), dim3(256), 0, stream>>>(
        hs, w_attn, b_attn, scores);

    // K2: one block per word
    coref_pool_kernel<<<dim3(N_WORDS), dim3(256), 0, stream>>>(
        hs, starts, ends, scores, out);
}

// Round 2
// 92.656 us; speedup vs baseline: 1.0431x; 1.0431x over previous
//
#include <hip/hip_runtime.h>
#include <hip/hip_bf16.h>
#include <math.h>

#define N_SUBWORDS 8192
#define N_WORDS    6000
#define HIDDEN     1024

// Fused single-pass kernel: one 256-thread block per word.
// For each subword s in the word's span:
//   1. all 256 threads cooperatively compute score(s) = dot(hs[s], w_attn) + b
//      (thread t covers dims [4t, 4t+4): float4 load + 4 FMA + block reduce)
//   2. online-softmax update of the per-thread float4 accumulator, REUSING the
//      row fragment h already in registers from step 1 (row read exactly once).
// Epilogue: acc /= l, store float4.
__global__ __launch_bounds__(256) void coref_fused_kernel(
    const float* __restrict__ hs,      // [N_SUBWORDS, HIDDEN]
    const int*   __restrict__ starts,  // [N_WORDS]
    const int*   __restrict__ ends,    // [N_WORDS] inclusive
    const float* __restrict__ w_attn,  // [HIDDEN]
    const float* __restrict__ b_attn,  // [1]
    float*       __restrict__ out)     // [N_WORDS, HIDDEN]
{
    // 2 slots x 4 waves: double-buffered partial sums so one __syncthreads
    // per span element suffices (iter i reads slot i&1, iter i+1 writes the
    // other slot; the i+1 barrier orders everything before slot reuse).
    __shared__ float red[8];

    const int w    = blockIdx.x;
    const int tid  = threadIdx.x;
    const int lane = tid & 63;
    const int wid  = tid >> 6;   // wave id 0..3

    const int s0 = starts[w];
    const int s1 = ends[w];      // inclusive, >= s0

    const float4 wv = ((const float4*)w_attn)[tid];  // this thread's w slice
    const float  b  = b_attn[0];

    float  m = 0.f, l = 1.f;
    float4 acc = make_float4(0.f, 0.f, 0.f, 0.f);

    for (int s = s0; s <= s1; ++s) {
        float4 h = ((const float4*)(hs + (size_t)s * HIDDEN))[tid];

        // partial dot over this thread's 4 dims
        float part = h.x * wv.x + h.y * wv.y + h.z * wv.z + h.w * wv.w;
        // wave-64 reduce
        #pragma unroll
        for (int off = 32; off > 0; off >>= 1)
            part += __shfl_down(part, off, 64);

        const int slot = ((s - s0) & 1) << 2;
        if (lane == 0) red[slot + wid] = part;
        __syncthreads();
        const float score =
            red[slot + 0] + red[slot + 1] + red[slot + 2] + red[slot + 3] + b;

        if (s == s0) {
            // first element: m = score, l = 1, acc = 1 * h
            m = score;
            l = 1.f;
            acc = h;
        } else {
            const float mn    = fmaxf(m, score);
            const float alpha = __expf(m - mn);      // rescale old state
            const float p     = __expf(score - mn);  // new element weight
            m = mn;
            l = l * alpha + p;
            acc.x = acc.x * alpha + p * h.x;
            acc.y = acc.y * alpha + p * h.y;
            acc.z = acc.z * alpha + p * h.z;
            acc.w = acc.w * alpha + p * h.w;
        }
    }

    const float inv_l = 1.f / l;
    float4 o;
    o.x = acc.x * inv_l;
    o.y = acc.y * inv_l;
    o.z = acc.z * inv_l;
    o.w = acc.w * inv_l;
    ((float4*)(out + (size_t)w * HIDDEN))[tid] = o;
}

extern "C" void kernel_launch(void* const* d_in, const int* in_sizes, int n_in,
                              void* d_out, int out_size, void* d_ws, size_t ws_size,
                              hipStream_t stream) {
    const float* hs     = (const float*)d_in[0];  // [8192*1024] f32
    const int*   starts = (const int*)d_in[1];    // [6000]
    const int*   ends   = (const int*)d_in[2];    // [6000]
    const float* w_attn = (const float*)d_in[3];  // [1024] f32
    const float* b_attn = (const float*)d_in[4];  // [1] f32
    float*       out    = (float*)d_out;          // [6000*1024] f32

    coref_fused_kernel<<<dim3(N_WORDS), dim3(256), 0, stream>>>(
        hs, starts, ends, w_attn, b_attn, out);
}

// Round 3
// 89.567 us; speedup vs baseline: 1.0791x; 1.0345x over previous
//
#include <hip/hip_runtime.h>
#include <hip/hip_bf16.h>
#include <math.h>

#define N_SUBWORDS 8192
#define N_WORDS    6000
#define HIDDEN     1024

// One WAVE per word. Lane l owns float4 chunks {l + 64j : j=0..3} of the
// 1024-dim row (4 KB row = 256 float4 = 64 lanes x 4 chunks, coalesced).
// Per span element:
//   1. load row fragment h[4] (4x float4)
//   2. partial dot with in-register w fragment, 6-step shfl_xor butterfly
//      reduce -> every lane holds the full score. No LDS, no barriers.
//   3. online-softmax update of acc[4], reusing h from registers.
// Epilogue: acc * (1/l) -> out row.
__global__ __launch_bounds__(256) void coref_fused_wave_kernel(
    const float* __restrict__ hs,      // [N_SUBWORDS, HIDDEN]
    const int*   __restrict__ starts,  // [N_WORDS]
    const int*   __restrict__ ends,    // [N_WORDS] inclusive
    const float* __restrict__ w_attn,  // [HIDDEN]
    const float* __restrict__ b_attn,  // [1]
    float*       __restrict__ out)     // [N_WORDS, HIDDEN]
{
    const int tid  = threadIdx.x;
    const int lane = tid & 63;
    const int w    = blockIdx.x * 4 + (tid >> 6);   // wave id -> word
    if (w >= N_WORDS) return;

    const int s0 = starts[w];
    const int s1 = ends[w];   // inclusive, >= s0

    const float4* __restrict__ wvp = (const float4*)w_attn;
    float4 wv[4];
#pragma unroll
    for (int j = 0; j < 4; ++j)
        wv[j] = wvp[lane + 64 * j];
    const float b = b_attn[0];

    float  m = 0.f, l = 1.f;
    float4 acc[4];

    for (int s = s0; s <= s1; ++s) {
        const float4* __restrict__ row = (const float4*)(hs + (size_t)s * HIDDEN);
        float4 h[4];
#pragma unroll
        for (int j = 0; j < 4; ++j)
            h[j] = row[lane + 64 * j];

        float part = 0.f;
#pragma unroll
        for (int j = 0; j < 4; ++j)
            part += h[j].x * wv[j].x + h[j].y * wv[j].y +
                    h[j].z * wv[j].z + h[j].w * wv[j].w;

        // wave-64 butterfly: every lane ends with the full sum
#pragma unroll
        for (int off = 32; off > 0; off >>= 1)
            part += __shfl_xor(part, off, 64);

        const float score = part + b;

        if (s == s0) {
            m = score;
            l = 1.f;
#pragma unroll
            for (int j = 0; j < 4; ++j)
                acc[j] = h[j];
        } else {
            const float mn    = fmaxf(m, score);
            const float alpha = __expf(m - mn);      // rescale old state
            const float p     = __expf(score - mn);  // new element weight
            m = mn;
            l = l * alpha + p;
#pragma unroll
            for (int j = 0; j < 4; ++j) {
                acc[j].x = acc[j].x * alpha + p * h[j].x;
                acc[j].y = acc[j].y * alpha + p * h[j].y;
                acc[j].z = acc[j].z * alpha + p * h[j].z;
                acc[j].w = acc[j].w * alpha + p * h[j].w;
            }
        }
    }

    const float inv_l = 1.f / l;
    float4* __restrict__ orow = (float4*)(out + (size_t)w * HIDDEN);
#pragma unroll
    for (int j = 0; j < 4; ++j) {
        float4 o;
        o.x = acc[j].x * inv_l;
        o.y = acc[j].y * inv_l;
        o.z = acc[j].z * inv_l;
        o.w = acc[j].w * inv_l;
        orow[lane + 64 * j] = o;
    }
}

extern "C" void kernel_launch(void* const* d_in, const int* in_sizes, int n_in,
                              void* d_out, int out_size, void* d_ws, size_t ws_size,
                              hipStream_t stream) {
    const float* hs     = (const float*)d_in[0];  // [8192*1024] f32
    const int*   starts = (const int*)d_in[1];    // [6000]
    const int*   ends   = (const int*)d_in[2];    // [6000]
    const float* w_attn = (const float*)d_in[3];  // [1024] f32
    const float* b_attn = (const float*)d_in[4];  // [1] f32
    float*       out    = (float*)d_out;          // [6000*1024] f32

    // 6000 words, one wave each, 4 waves per 256-thread block -> 1500 blocks
    coref_fused_wave_kernel<<<dim3((N_WORDS + 3) / 4), dim3(256), 0, stream>>>(
        hs, starts, ends, w_attn, b_attn, out);
}